// Round 4
// baseline (446.874 us; speedup 1.0000x reference)
//
#include <hip/hip_runtime.h>
#include <math.h>

typedef _Float16 v8h __attribute__((ext_vector_type(8)));
typedef float v4f __attribute__((ext_vector_type(4)));
typedef float v16f __attribute__((ext_vector_type(16)));

// ---------------------------------------------------------------- prep (repack + mlp + convert merged)
// R3: weight repack LDS-staged for coalescing (prep dropped out of top-5).
// blocks [0,32):    rc repack, 4 co per block
// blocks [32,128):  bb repack, conv k=(bx-32)/16, co-group g=(bx-32)%16 (8 co)
// blocks [128,135): dp copy (flat, coalesced)
// block  135:       tiny MLP + SE sigmoid
// blocks [136,360): NCHW f32 -> NHWC f16 convert, thread=w, v8h stores
__global__ void __launch_bounds__(256) prep_kernel(
    const float* __restrict__ rc_w, const float* __restrict__ bb_w1,
    const float* __restrict__ bb_w2, const float* __restrict__ dp_w,
    const float* __restrict__ img, const float* __restrict__ sps,
    const float* __restrict__ fc1_w, const float* __restrict__ fc1_b,
    const float* __restrict__ fc2_w, const float* __restrict__ fc2_b,
    const float* __restrict__ se_rw, const float* __restrict__ se_rb,
    const float* __restrict__ se_ew, const float* __restrict__ se_eb,
    _Float16* __restrict__ wrc, _Float16* __restrict__ wbb,
    _Float16* __restrict__ wdp, _Float16* __restrict__ act16,
    float* __restrict__ sig) {
  const int bx = blockIdx.x;
  const int tid = threadIdx.x;
  __shared__ float lds[9224];  // 36,896 B; padded weight stage / mlp buf

  if (bx < 32) {  // ---- rc repack: co-group of 4, src 4x2304 f32 coalesced
    const float* src = rc_w + (size_t)bx * 4 * 2304;
#pragma unroll
    for (int r = 0; r < 36; ++r) {
      int e = r * 256 + tid;            // 0..9215
      int col = e / 2304;               // 0..3
      int rem = e - col * 2304;
      lds[col * 2305 + rem] = src[e];   // +1 pad breaks col-bank aliasing
    }
    __syncthreads();
#pragma unroll
    for (int ro = 0; ro < 5; ++ro) {
      int lidx = ro * 256 + tid;  // 1152 slots = 16 c16 x 9 tap x 2 kh x 4 col
      if (lidx < 1152) {
        int col = lidx & 3;
        int r = lidx >> 2;        // ((c16*9+tap)*2+kh)
        int kh = r & 1;
        int ct = r >> 1;
        int tap = ct % 9, c16 = ct / 9;
        v8h o;
#pragma unroll
        for (int j = 0; j < 8; ++j)
          o[j] = (_Float16)lds[col * 2305 + (c16 * 16 + kh * 8 + j) * 9 + tap];
        *(v8h*)(wrc + ((size_t)r * 128 + bx * 4 + col) * 8) = o;
      }
    }
  } else if (bx < 128) {  // ---- bb repack: conv k, co-group of 8
    const int t = bx - 32;
    const int k = t >> 4, g = t & 15;
    const float* base = (k < 3) ? (bb_w1 + (size_t)k * 147456)
                                : (bb_w2 + (size_t)(k - 3) * 147456);
    const int cslot = (k < 3) ? (2 * k) : (2 * (k - 3) + 1);
    const float* src = base + (size_t)g * 8 * 1152;
#pragma unroll
    for (int r = 0; r < 36; ++r) {
      int e = r * 256 + tid;            // 0..9215
      int col = e / 1152;               // 0..7
      int rem = e - col * 1152;
      lds[col * 1153 + rem] = src[e];
    }
    __syncthreads();
#pragma unroll
    for (int ro = 0; ro < 5; ++ro) {
      int lidx = ro * 256 + tid;  // 1152 slots = 8 c16 x 9 tap x 2 kh x 8 col
      if (lidx < 1152) {
        int col = lidx & 7;
        int r = lidx >> 3;        // ((c16*9+tap)*2+kh), c16<8
        int kh = r & 1;
        int ct = r >> 1;
        int tap = ct % 9, c16 = ct / 9;
        v8h o;
#pragma unroll
        for (int j = 0; j < 8; ++j)
          o[j] = (_Float16)lds[col * 1153 + (c16 * 16 + kh * 8 + j) * 9 + tap];
        *(v8h*)(wbb + (size_t)cslot * 147456 + ((size_t)r * 128 + g * 8 + col) * 8) = o;
      }
    }
  } else if (bx < 135) {  // ---- dp: flat, coalesced both sides
    int s3 = (bx - 128) * 256 + tid;  // < 1792
    v8h o;
#pragma unroll
    for (int j = 0; j < 8; ++j) o[j] = (_Float16)dp_w[(size_t)s3 * 8 + j];
    *(v8h*)(wdp + (size_t)s3 * 8) = o;
  } else if (bx == 135) {  // ---- mlp (first 128 lanes compute; barriers uniform)
    const int j = tid;
    const bool on = j < 128;
    for (int b = 0; b < 4; ++b) {
      float h1 = 0.f;
      if (on) h1 = fmaxf(sps[b] * fc1_w[j] + fc1_b[j], 0.f);
      __syncthreads();
      if (on) lds[j] = h1;
      __syncthreads();
      float hm = 0.f;
      if (on) {
        hm = fc2_b[j];
        for (int k = 0; k < 128; ++k) hm += lds[k] * fc2_w[j * 128 + k];
      }
      __syncthreads();
      if (on) lds[j] = hm;
      __syncthreads();
      float t = 0.f;
      if (on) {
        t = se_rb[j];
        for (int k = 0; k < 128; ++k) t += lds[k] * se_rw[j * 128 + k];
        t = fmaxf(t, 0.f);
      }
      __syncthreads();
      if (on) lds[j] = t;
      __syncthreads();
      if (on) {
        float se = se_eb[j];
        for (int k = 0; k < 128; ++k) se += lds[k] * se_ew[j * 128 + k];
        sig[b * 128 + j] = 1.f / (1.f + expf(-se));
      }
      __syncthreads();
    }
  } else {  // ---- convert: block = (n,h); thread = w; 8-ch gather -> v8h store
    const int bid = bx - 136;
    const int n = bid / 56, h = bid - n * 56;
    const int w = tid;
    if (w < 200) {
      const float* ip = img + ((size_t)n * 256 * 56 + h) * 200 + w;
      _Float16* op = act16 + (((size_t)n * 56 + h) * 200 + w) * 256;
#pragma unroll 4
      for (int c8 = 0; c8 < 32; ++c8) {
        v8h o;
#pragma unroll
        for (int j = 0; j < 8; ++j)
          o[j] = (_Float16)ip[(size_t)(c8 * 8 + j) * 11200];  // 56*200
        *(v8h*)(op + c8 * 8) = o;
      }
    }
  }
}

// ---------------------------------------------------------------- 3x3 conv, implicit GEMM, 32x32x16 f16 MFMA
// R4: LDS-bandwidth diet. R3 counters: MfmaUtil pinned ~25% across 3 configs,
// LDS reads = 27 b128/chunk/wave (1.5 per MFMA) ~= 31 us of LDS time in a
// 48 us kernel => LDS-BW-bound, not latency-bound. Two changes:
//  1. B weights bypass LDS: per chunk each wave loads its 9 tap-fragments
//     (9 KB, shared by 196 waves -> L2-resident) straight to registers.
//     Kills 1/3 of LDS reads + all B LDS writes; LDS = A dbuf only (21.8 KB).
//  2. dy-reuse of A: for fixed dx the 6 MFMAs (2 mt x 3 dy) touch only 4
//     distinct A rows -> read 4 rows once per dx (12 reads/chunk, was 18).
// Net: 12 LDS reads per 18 MFMAs (0.67/MFMA); LDS read time ~12 us vs MFMA
// floor 11.8 us -- balanced. Grid/tile unchanged from R3 (784 blocks, 4 waves,
// wave = 2h x 32w x 32cout).
// MODE 0: out = relu((conv + bias)*s + t) * sig_se          (rc conv)
// MODE 1: out = relu(conv*s + t)                            (bb conv1)
// MODE 2: out = relu(xprev + conv*s + t)                    (bb conv2 + residual)
template <int CIN, int MODE>
__global__ void __launch_bounds__(256, 4) conv3x3_kernel(
    const _Float16* __restrict__ act, const _Float16* __restrict__ wr,
    const _Float16* __restrict__ xprev, const float* __restrict__ bias,
    const float* __restrict__ sc, const float* __restrict__ tr,
    const float* __restrict__ sig_se, _Float16* __restrict__ out) {
  constexpr int NCH = CIN / 16;
  const int wt = blockIdx.x, ht = blockIdx.y;
  const int n = blockIdx.z >> 2, cq = blockIdx.z & 3;
  const int h0 = ht * 8, w0 = wt * 32;
  const int tid = threadIdx.x;
  const int wave = tid >> 6, lane = tid & 63;
  const int l31 = lane & 31, khalf = lane >> 5;
  const int wv = wave;  // h-pair index 0..3

  __shared__ alignas(16) _Float16 ldsA[2][2 * 340 * 8];  // 10,880 B per buf

  // ---- A staging map: 680 v8h slots (2 parts x 340 pos) over 3 rounds
  size_t goffA[3];
  int loffA[3];
  bool exA[3], okA[3];
#pragma unroll
  for (int it = 0; it < 3; ++it) {
    int slot = it * 256 + tid;
    int pos = slot >> 1, part = slot & 1;  // 2 lanes = 32B contiguous global
    int hh = pos / 34, ww = pos - hh * 34;
    int gh = h0 - 1 + hh, gw = w0 - 1 + ww;
    exA[it] = slot < 680;
    bool inimg = (unsigned)gh < 56u && (unsigned)gw < 200u;
    okA[it] = exA[it] && inimg;
    loffA[it] = (part * 340 + pos) * 8;
    int ghc = okA[it] ? gh : 0, gwc = okA[it] ? gw : 0;
    goffA[it] = (((size_t)n * 56 + ghc) * 200 + gwc) * CIN + part * 8;
  }
  // ---- B base: this lane's (khalf, cout) column; per (chunk,tap) offset is
  //      (c*2304 + tap*256)*8 elems. Lanes 0-31 and 32-63 each span 512B runs.
  const _Float16* wbase = wr + ((size_t)khalf * 128 + cq * 32 + l31) * 8;

  const v8h zero8 = {(_Float16)0, (_Float16)0, (_Float16)0, (_Float16)0,
                     (_Float16)0, (_Float16)0, (_Float16)0, (_Float16)0};
  v8h preA[3];
#pragma unroll
  for (int it = 0; it < 3; ++it) preA[it] = okA[it] ? *(const v8h*)(act + goffA[it]) : zero8;

  v16f acc[2];
#pragma unroll
  for (int mt = 0; mt < 2; ++mt)
#pragma unroll
    for (int r = 0; r < 16; ++r) acc[mt][r] = 0.f;

#pragma unroll 1
  for (int c = 0; c < NCH; ++c) {
    _Float16* aB = &ldsA[c & 1][0];
    // commit prefetched A chunk
#pragma unroll
    for (int it = 0; it < 3; ++it)
      if (exA[it]) *(v8h*)(aB + loffA[it]) = preA[it];
    // issue B loads for this chunk (L2 hits; in flight across the barrier)
    v8h bfr[9];
#pragma unroll
    for (int tap = 0; tap < 9; ++tap)
      bfr[tap] = *(const v8h*)(wbase + ((size_t)c * 2304 + tap * 256) * 8);
    __syncthreads();
    // prefetch next A chunk (hidden behind this chunk's MFMA block)
    if (c + 1 < NCH) {
#pragma unroll
      for (int it = 0; it < 3; ++it)
        preA[it] = okA[it] ? *(const v8h*)(act + goffA[it] + (size_t)(c + 1) * 16) : zero8;
    }
#pragma unroll
    for (int dx = 0; dx < 3; ++dx) {
      v8h a[4];
#pragma unroll
      for (int r = 0; r < 4; ++r)
        a[r] = *(const v8h*)(aB + (khalf * 340 + (wv * 2 + r) * 34 + l31 + dx) * 8);
#pragma unroll
      for (int dy = 0; dy < 3; ++dy) {
        const v8h bf = bfr[dy * 3 + dx];
        acc[0] = __builtin_amdgcn_mfma_f32_32x32x16_f16(a[dy], bf, acc[0], 0, 0, 0);
        acc[1] = __builtin_amdgcn_mfma_f32_32x32x16_f16(a[dy + 1], bf, acc[1], 0, 0, 0);
      }
    }
  }

  // epilogue: D layout col(N=cout)=l31, row(M=w-offset)=(r&3)+8*(r>>2)+4*khalf
#pragma unroll
  for (int mt = 0; mt < 2; ++mt) {
    const int h = h0 + wv * 2 + mt;
    const int cc = cq * 32 + l31;
    const float s = sc[cc], t = tr[cc];
    float bb = 0.f, sg = 1.f;
    if constexpr (MODE == 0) {
      bb = bias[cc];
      sg = sig_se[n * 128 + cc];
    }
#pragma unroll
    for (int r = 0; r < 16; ++r) {
      const int m = (r & 3) + 8 * (r >> 2) + 4 * khalf;
      const int w = w0 + m;
      if (w < 200) {
        float v = acc[mt][r];
        size_t oidx = (((size_t)n * 56 + h) * 200 + w) * 128 + cc;
        if constexpr (MODE == 0) v = fmaxf((v + bb) * s + t, 0.f) * sg;
        if constexpr (MODE == 1) v = fmaxf(v * s + t, 0.f);
        if constexpr (MODE == 2) v = fmaxf((float)xprev[oidx] + v * s + t, 0.f);
        out[oidx] = (_Float16)v;
      }
    }
  }
}

// ---------------------------------------------------------------- depth proj (MFMA) + fused softmax
// x: [44800][128] f16; wdp: [112][128] f16; dp_b: [112] f32
// depth out: f16 [pos][112] (z-contiguous for gridsample)
__global__ void __launch_bounds__(256) depth_proj_softmax_kernel(
    const _Float16* __restrict__ x, const _Float16* __restrict__ wdp,
    const float* __restrict__ dp_b, _Float16* __restrict__ depth) {
  const int wave = threadIdx.x >> 6, lane = threadIdx.x & 63;
  const int q = lane >> 4, l16 = lane & 15;
  const int pos0 = blockIdx.x * 64 + wave * 16;

  v4f acc[7];
#pragma unroll
  for (int nt = 0; nt < 7; ++nt) {
    float bv = dp_b[nt * 16 + l16];
    acc[nt] = {bv, bv, bv, bv};
  }
#pragma unroll
  for (int c0 = 0; c0 < 128; c0 += 32) {
    v8h a = *(const v8h*)(x + (size_t)(pos0 + l16) * 128 + c0 + q * 8);
#pragma unroll
    for (int nt = 0; nt < 7; ++nt) {
      v8h b = *(const v8h*)(wdp + (size_t)(nt * 16 + l16) * 128 + c0 + q * 8);
      acc[nt] = __builtin_amdgcn_mfma_f32_16x16x32_f16(a, b, acc[nt], 0, 0, 0);
    }
  }
  float m[4];
#pragma unroll
  for (int r = 0; r < 4; ++r) {
    m[r] = acc[0][r];
#pragma unroll
    for (int nt = 1; nt < 7; ++nt) m[r] = fmaxf(m[r], acc[nt][r]);
  }
#pragma unroll
  for (int off = 1; off < 16; off <<= 1)
#pragma unroll
    for (int r = 0; r < 4; ++r) m[r] = fmaxf(m[r], __shfl_xor(m[r], off));
  float s[4] = {0.f, 0.f, 0.f, 0.f};
#pragma unroll
  for (int nt = 0; nt < 7; ++nt)
#pragma unroll
    for (int r = 0; r < 4; ++r) {
      float e = expf(acc[nt][r] - m[r]);
      acc[nt][r] = e;
      s[r] += e;
    }
#pragma unroll
  for (int off = 1; off < 16; off <<= 1)
#pragma unroll
    for (int r = 0; r < 4; ++r) s[r] += __shfl_xor(s[r], off);
#pragma unroll
  for (int r = 0; r < 4; ++r) {
    const float inv = 1.f / s[r];
    const size_t p = pos0 + q * 4 + r;
#pragma unroll
    for (int nt = 0; nt < 7; ++nt)
      depth[p * 112 + nt * 16 + l16] = (_Float16)(acc[nt][r] * inv);
  }
}

// ---------------------------------------------------------------- trilinear grid sample (C=1)
__global__ void __launch_bounds__(256) gridsample_kernel(
    const float* __restrict__ grids, const _Float16* __restrict__ depth,
    float* __restrict__ out) {
  const int i = blockIdx.x * 256 + threadIdx.x;
  const int n = i >> 18;
  const float gx = grids[(size_t)i * 3];
  const float gy = grids[(size_t)i * 3 + 1];
  const float gz = grids[(size_t)i * 3 + 2];
  const float ix = (gx + 1.f) * 100.f - 0.5f;
  const float iy = (gy + 1.f) * 28.f - 0.5f;
  const float iz = (gz + 1.f) * 56.f - 0.5f;
  const float xf = floorf(ix), yf = floorf(iy), zf = floorf(iz);
  const int x0 = (int)xf, y0 = (int)yf, z0 = (int)zf;
  const float fx = ix - xf, fy = iy - yf, fz = iz - zf;
  const bool zv0 = (unsigned)z0 < 112u;
  const bool zv1 = (unsigned)(z0 + 1) < 112u;
  const float wz0 = 1.f - fz, wz1 = fz;
  float acc = 0.f;
#pragma unroll
  for (int dy = 0; dy < 2; ++dy) {
    const int yi = y0 + dy;
    const float wy = dy ? fy : 1.f - fy;
#pragma unroll
    for (int dx = 0; dx < 2; ++dx) {
      const int xi = x0 + dx;
      const float wx = dx ? fx : 1.f - fx;
      if ((unsigned)xi < 200u && (unsigned)yi < 56u) {
        const _Float16* bp = depth + ((size_t)n * 11200 + yi * 200 + xi) * 112;
        float v0 = zv0 ? (float)bp[z0] : 0.f;
        float v1 = zv1 ? (float)bp[z0 + 1] : 0.f;
        acc += (wx * wy) * (wz0 * v0 + wz1 * v1);
      }
    }
  }
  out[i] = acc;
}

// ---------------------------------------------------------------- launch
extern "C" void kernel_launch(void* const* d_in, const int* in_sizes, int n_in,
                              void* d_out, int out_size, void* d_ws, size_t ws_size,
                              hipStream_t stream) {
  (void)in_sizes; (void)n_in; (void)out_size; (void)ws_size;
  const float* img = (const float*)d_in[0];
  const float* sps = (const float*)d_in[1];
  const float* grids = (const float*)d_in[2];
  const float* rc_w = (const float*)d_in[3];
  const float* rc_b = (const float*)d_in[4];
  const float* rc_s = (const float*)d_in[5];
  const float* rc_t = (const float*)d_in[6];
  const float* fc1_w = (const float*)d_in[7];
  const float* fc1_b = (const float*)d_in[8];
  const float* fc2_w = (const float*)d_in[9];
  const float* fc2_b = (const float*)d_in[10];
  const float* se_rw = (const float*)d_in[11];
  const float* se_rb = (const float*)d_in[12];
  const float* se_ew = (const float*)d_in[13];
  const float* se_eb = (const float*)d_in[14];
  const float* bb_w1 = (const float*)d_in[15];
  const float* bb_s1 = (const float*)d_in[16];
  const float* bb_t1 = (const float*)d_in[17];
  const float* bb_w2 = (const float*)d_in[18];
  const float* bb_s2 = (const float*)d_in[19];
  const float* bb_t2 = (const float*)d_in[20];
  const float* dp_w = (const float*)d_in[21];
  const float* dp_b = (const float*)d_in[22];
  float* outp = (float*)d_out;

  char* ws = (char*)d_ws;
  _Float16* act16 = (_Float16*)(ws + 0);
  _Float16* depth16 = (_Float16*)(ws + 0);  // reuses act16 slot (act16 dead post rc-conv)
  _Float16* xa = (_Float16*)(ws + 23068672);
  _Float16* xb = (_Float16*)(ws + 23068672 + 11534336);
  _Float16* yb = (_Float16*)(ws + 23068672 + 2 * 11534336);
  _Float16* wrc = (_Float16*)(ws + 57671680);           // 589,824 B
  _Float16* wdp = (_Float16*)(ws + 57671680 + 589824);  // 28,672 B
  _Float16* wbb = (_Float16*)(ws + 58327040);           // 1,769,472 B
  float* sig = (float*)(ws + 58327040 + 1769472);       // 2,048 B

  prep_kernel<<<dim3(360), 256, 0, stream>>>(
      rc_w, bb_w1, bb_w2, dp_w, img, sps, fc1_w, fc1_b, fc2_w, fc2_b, se_rw, se_rb,
      se_ew, se_eb, wrc, wbb, wdp, act16, sig);

  dim3 cgrid(7, 7, 16);  // 8h x 32w x 32cout, z = n*4 + cq, 784 blocks x 4 waves
  conv3x3_kernel<256, 0><<<cgrid, 256, 0, stream>>>(act16, wrc, nullptr, rc_b, rc_s,
                                                    rc_t, sig, xa);
  _Float16* xcur = xa;
  _Float16* xnxt = xb;
  for (int i = 0; i < 3; ++i) {
    conv3x3_kernel<128, 1><<<cgrid, 256, 0, stream>>>(
        xcur, wbb + (size_t)(2 * i) * 147456, nullptr, nullptr, bb_s1 + i * 128,
        bb_t1 + i * 128, nullptr, yb);
    conv3x3_kernel<128, 2><<<cgrid, 256, 0, stream>>>(
        yb, wbb + (size_t)(2 * i + 1) * 147456, xcur, nullptr, bb_s2 + i * 128,
        bb_t2 + i * 128, nullptr, xnxt);
    _Float16* t = xcur;
    xcur = xnxt;
    xnxt = t;
  }

  depth_proj_softmax_kernel<<<dim3(700), 256, 0, stream>>>(xcur, wdp, dp_b, depth16);
  gridsample_kernel<<<dim3(4096), 256, 0, stream>>>(grids, depth16, outp);
}

// Round 5
// 407.015 us; speedup vs baseline: 1.0979x; 1.0979x over previous
//
#include <hip/hip_runtime.h>
#include <math.h>

typedef _Float16 v8h __attribute__((ext_vector_type(8)));
typedef float v4f __attribute__((ext_vector_type(4)));
typedef float v16f __attribute__((ext_vector_type(16)));

// ---------------------------------------------------------------- prep (repack + mlp + convert merged)
// R5: convert section re-gridded for occupancy. R4 counters: prep 44 us at
// 0.9 TB/s, VALU 2% -> latency-bound: only 224 convert blocks (some CUs got
// none), 200/256 threads, 256 serial gathers/thread. Now 896 convert blocks
// (n,h,cq): each thread does 64 gathers; ~4x waves.
// blocks [0,32):    rc repack, 4 co per block (LDS transpose, coalesced)
// blocks [32,128):  bb repack, conv k=(bx-32)/16, co-group g=(bx-32)%16 (8 co)
// blocks [128,135): dp copy (flat, coalesced)
// block  135:       tiny MLP + SE sigmoid
// blocks [136,1032): NCHW f32 -> NHWC f16 convert, block=(n,h,cq), thread=w
__global__ void __launch_bounds__(256) prep_kernel(
    const float* __restrict__ rc_w, const float* __restrict__ bb_w1,
    const float* __restrict__ bb_w2, const float* __restrict__ dp_w,
    const float* __restrict__ img, const float* __restrict__ sps,
    const float* __restrict__ fc1_w, const float* __restrict__ fc1_b,
    const float* __restrict__ fc2_w, const float* __restrict__ fc2_b,
    const float* __restrict__ se_rw, const float* __restrict__ se_rb,
    const float* __restrict__ se_ew, const float* __restrict__ se_eb,
    _Float16* __restrict__ wrc, _Float16* __restrict__ wbb,
    _Float16* __restrict__ wdp, _Float16* __restrict__ act16,
    float* __restrict__ sig) {
  const int bx = blockIdx.x;
  const int tid = threadIdx.x;
  __shared__ float lds[9224];  // 36,896 B; padded weight stage / mlp buf

  if (bx < 32) {  // ---- rc repack: co-group of 4, src 4x2304 f32 coalesced
    const float* src = rc_w + (size_t)bx * 4 * 2304;
#pragma unroll
    for (int r = 0; r < 36; ++r) {
      int e = r * 256 + tid;            // 0..9215
      int col = e / 2304;               // 0..3
      int rem = e - col * 2304;
      lds[col * 2305 + rem] = src[e];   // +1 pad breaks col-bank aliasing
    }
    __syncthreads();
#pragma unroll
    for (int ro = 0; ro < 5; ++ro) {
      int lidx = ro * 256 + tid;  // 1152 slots = 16 c16 x 9 tap x 2 kh x 4 col
      if (lidx < 1152) {
        int col = lidx & 3;
        int r = lidx >> 2;        // ((c16*9+tap)*2+kh)
        int kh = r & 1;
        int ct = r >> 1;
        int tap = ct % 9, c16 = ct / 9;
        v8h o;
#pragma unroll
        for (int j = 0; j < 8; ++j)
          o[j] = (_Float16)lds[col * 2305 + (c16 * 16 + kh * 8 + j) * 9 + tap];
        *(v8h*)(wrc + ((size_t)r * 128 + bx * 4 + col) * 8) = o;
      }
    }
  } else if (bx < 128) {  // ---- bb repack: conv k, co-group of 8
    const int t = bx - 32;
    const int k = t >> 4, g = t & 15;
    const float* base = (k < 3) ? (bb_w1 + (size_t)k * 147456)
                                : (bb_w2 + (size_t)(k - 3) * 147456);
    const int cslot = (k < 3) ? (2 * k) : (2 * (k - 3) + 1);
    const float* src = base + (size_t)g * 8 * 1152;
#pragma unroll
    for (int r = 0; r < 36; ++r) {
      int e = r * 256 + tid;            // 0..9215
      int col = e / 1152;               // 0..7
      int rem = e - col * 1152;
      lds[col * 1153 + rem] = src[e];
    }
    __syncthreads();
#pragma unroll
    for (int ro = 0; ro < 5; ++ro) {
      int lidx = ro * 256 + tid;  // 1152 slots = 8 c16 x 9 tap x 2 kh x 8 col
      if (lidx < 1152) {
        int col = lidx & 7;
        int r = lidx >> 3;        // ((c16*9+tap)*2+kh), c16<8
        int kh = r & 1;
        int ct = r >> 1;
        int tap = ct % 9, c16 = ct / 9;
        v8h o;
#pragma unroll
        for (int j = 0; j < 8; ++j)
          o[j] = (_Float16)lds[col * 1153 + (c16 * 16 + kh * 8 + j) * 9 + tap];
        *(v8h*)(wbb + (size_t)cslot * 147456 + ((size_t)r * 128 + g * 8 + col) * 8) = o;
      }
    }
  } else if (bx < 135) {  // ---- dp: flat, coalesced both sides
    int s3 = (bx - 128) * 256 + tid;  // < 1792
    v8h o;
#pragma unroll
    for (int j = 0; j < 8; ++j) o[j] = (_Float16)dp_w[(size_t)s3 * 8 + j];
    *(v8h*)(wdp + (size_t)s3 * 8) = o;
  } else if (bx == 135) {  // ---- mlp (first 128 lanes compute; barriers uniform)
    const int j = tid;
    const bool on = j < 128;
    for (int b = 0; b < 4; ++b) {
      float h1 = 0.f;
      if (on) h1 = fmaxf(sps[b] * fc1_w[j] + fc1_b[j], 0.f);
      __syncthreads();
      if (on) lds[j] = h1;
      __syncthreads();
      float hm = 0.f;
      if (on) {
        hm = fc2_b[j];
        for (int k = 0; k < 128; ++k) hm += lds[k] * fc2_w[j * 128 + k];
      }
      __syncthreads();
      if (on) lds[j] = hm;
      __syncthreads();
      float t = 0.f;
      if (on) {
        t = se_rb[j];
        for (int k = 0; k < 128; ++k) t += lds[k] * se_rw[j * 128 + k];
        t = fmaxf(t, 0.f);
      }
      __syncthreads();
      if (on) lds[j] = t;
      __syncthreads();
      if (on) {
        float se = se_eb[j];
        for (int k = 0; k < 128; ++k) se += lds[k] * se_ew[j * 128 + k];
        sig[b * 128 + j] = 1.f / (1.f + expf(-se));
      }
      __syncthreads();
    }
  } else {  // ---- convert: block = (n,h,cq); thread = w; 8 c8-groups per block
    const int bid = bx - 136;  // 0..895
    const int cq = bid & 3;
    const int t = bid >> 2;
    const int n = t / 56, h = t - n * 56;
    const int w = tid;
    if (w < 200) {
      const float* ip = img + ((size_t)n * 256 * 56 + h) * 200 + w;
      _Float16* op = act16 + (((size_t)n * 56 + h) * 200 + w) * 256;
#pragma unroll
      for (int c8 = cq * 8; c8 < cq * 8 + 8; ++c8) {
        v8h o;
#pragma unroll
        for (int j = 0; j < 8; ++j)
          o[j] = (_Float16)ip[(size_t)(c8 * 8 + j) * 11200];  // 56*200
        *(v8h*)(op + c8 * 8) = o;
      }
    }
  }
}

// ---------------------------------------------------------------- 3x3 conv, implicit GEMM, 32x32x16 f16 MFMA
// R5: exact revert to the R2 configuration -- empirically best of 4 tested
// (43.0 us rc conv; FETCH 28 MB). R3/R4 taught: (a) 32-cout blocks 4x A
// re-reads (act16 23MB >> 4MiB/XCD L2) -> +5-8 us; (b) B-from-L2 + dy-reuse
// cut LDS reads but slowed it down -> LDS BW was not the binding pipe.
// Tile: 8h x 32w x 64cout, grid 7x7x8 = 392 blocks, 512 thr / 8 waves,
// wave tile 2h x 32w x 32cout (wv=wave>>1 h-pair, kc=wave&1 cout half).
// Chunk = 16 channels; VGPR-prefetch A halo (2 rounds) + B slice (3 rounds)
// during previous chunk's compute; one barrier per chunk. LDS 58.6 KB ->
// 2 blocks/CU.
// MODE 0: out = relu((conv + bias)*s + t) * sig_se          (rc conv)
// MODE 1: out = relu(conv*s + t)                            (bb conv1)
// MODE 2: out = relu(xprev + conv*s + t)                    (bb conv2 + residual)
template <int CIN, int MODE>
__global__ void __launch_bounds__(512, 4) conv3x3_kernel(
    const _Float16* __restrict__ act, const _Float16* __restrict__ wr,
    const _Float16* __restrict__ xprev, const float* __restrict__ bias,
    const float* __restrict__ sc, const float* __restrict__ tr,
    const float* __restrict__ sig_se, _Float16* __restrict__ out) {
  constexpr int NCH = CIN / 16;
  const int wt = blockIdx.x, ht = blockIdx.y;
  const int n = blockIdx.z >> 1, cg = blockIdx.z & 1;
  const int h0 = ht * 8, w0 = wt * 32;
  const int tid = threadIdx.x;
  const int wave = tid >> 6, lane = tid & 63;
  const int l31 = lane & 31, khalf = lane >> 5;
  const int wv = wave >> 1, kc = wave & 1;

  __shared__ alignas(16) _Float16 ldsA[2][2 * 340 * 8];  // 10,880 B per buf
  __shared__ alignas(16) _Float16 ldsB[2][1152 * 8];     // 18,432 B per buf

  // ---- A staging map: 680 v8h slots (2 parts x 340 pos) over 2 rounds
  size_t goffA[2];
  int loffA[2];
  bool exA[2], okA[2];
#pragma unroll
  for (int it = 0; it < 2; ++it) {
    int slot = it * 512 + tid;
    int pos = slot >> 1, part = slot & 1;  // 2 lanes = 32B contiguous global
    int hh = pos / 34, ww = pos - hh * 34;
    int gh = h0 - 1 + hh, gw = w0 - 1 + ww;
    exA[it] = slot < 680;
    bool inimg = (unsigned)gh < 56u && (unsigned)gw < 200u;
    okA[it] = exA[it] && inimg;
    loffA[it] = (part * 340 + pos) * 8;
    int ghc = okA[it] ? gh : 0, gwc = okA[it] ? gw : 0;
    goffA[it] = (((size_t)n * 56 + ghc) * 200 + gwc) * CIN + part * 8;
  }
  // ---- B staging map: 1152 v8h slots (9 tap x 2 kh x 64 cout) over 3 rounds
  size_t goffB[3];
  int loffB[3];
  bool exB[3];
#pragma unroll
  for (int it = 0; it < 3; ++it) {
    int slot = it * 512 + tid;
    exB[it] = slot < 1152;
    int s = exB[it] ? slot : 0;
    int tap = s >> 7, kh = (s >> 6) & 1, co = s & 63;
    goffB[it] = (((size_t)(tap * 2 + kh)) * 128 + cg * 64 + co) * 8;  // chunk-0 offset
    loffB[it] = s * 8;
  }

  const v8h zero8 = {(_Float16)0, (_Float16)0, (_Float16)0, (_Float16)0,
                     (_Float16)0, (_Float16)0, (_Float16)0, (_Float16)0};
  v8h preA[2], preB[3];
#pragma unroll
  for (int it = 0; it < 2; ++it) preA[it] = okA[it] ? *(const v8h*)(act + goffA[it]) : zero8;
#pragma unroll
  for (int it = 0; it < 3; ++it) preB[it] = exB[it] ? *(const v8h*)(wr + goffB[it]) : zero8;

  v16f acc[2];
#pragma unroll
  for (int mt = 0; mt < 2; ++mt)
#pragma unroll
    for (int r = 0; r < 16; ++r) acc[mt][r] = 0.f;

#pragma unroll 1
  for (int c = 0; c < NCH; ++c) {
    _Float16* aB = &ldsA[c & 1][0];
    _Float16* bB = &ldsB[c & 1][0];
    // commit prefetched chunk
#pragma unroll
    for (int it = 0; it < 2; ++it)
      if (exA[it]) *(v8h*)(aB + loffA[it]) = preA[it];
#pragma unroll
    for (int it = 0; it < 3; ++it)
      if (exB[it]) *(v8h*)(bB + loffB[it]) = preB[it];
    __syncthreads();
    // prefetch next chunk (batched; hidden behind this chunk's MFMA block)
    if (c + 1 < NCH) {
#pragma unroll
      for (int it = 0; it < 2; ++it)
        preA[it] = okA[it] ? *(const v8h*)(act + goffA[it] + (size_t)(c + 1) * 16) : zero8;
#pragma unroll
      for (int it = 0; it < 3; ++it)
        preB[it] = exB[it] ? *(const v8h*)(wr + goffB[it] + (size_t)(c + 1) * 18432) : zero8;
    }
#pragma unroll
    for (int dy = 0; dy < 3; ++dy) {
#pragma unroll
      for (int dx = 0; dx < 3; ++dx) {
        const int tap = dy * 3 + dx;
        v8h bfrag = *(const v8h*)(bB + (tap * 128 + khalf * 64 + kc * 32 + l31) * 8);
#pragma unroll
        for (int mt = 0; mt < 2; ++mt) {
          const int pos = (wv * 2 + mt + dy) * 34 + l31 + dx;
          v8h afrag = *(const v8h*)(aB + (khalf * 340 + pos) * 8);
          acc[mt] = __builtin_amdgcn_mfma_f32_32x32x16_f16(afrag, bfrag, acc[mt], 0, 0, 0);
        }
      }
    }
  }

  // epilogue: D layout col(N=cout)=l31, row(M=w-offset)=(r&3)+8*(r>>2)+4*khalf
#pragma unroll
  for (int mt = 0; mt < 2; ++mt) {
    const int h = h0 + wv * 2 + mt;
    const int cc = cg * 64 + kc * 32 + l31;
    const float s = sc[cc], t = tr[cc];
    float bb = 0.f, sg = 1.f;
    if constexpr (MODE == 0) {
      bb = bias[cc];
      sg = sig_se[n * 128 + cc];
    }
#pragma unroll
    for (int r = 0; r < 16; ++r) {
      const int m = (r & 3) + 8 * (r >> 2) + 4 * khalf;
      const int w = w0 + m;
      if (w < 200) {
        float v = acc[mt][r];
        size_t oidx = (((size_t)n * 56 + h) * 200 + w) * 128 + cc;
        if constexpr (MODE == 0) v = fmaxf((v + bb) * s + t, 0.f) * sg;
        if constexpr (MODE == 1) v = fmaxf(v * s + t, 0.f);
        if constexpr (MODE == 2) v = fmaxf((float)xprev[oidx] + v * s + t, 0.f);
        out[oidx] = (_Float16)v;
      }
    }
  }
}

// ---------------------------------------------------------------- depth proj (MFMA) + fused softmax
// x: [44800][128] f16; wdp: [112][128] f16; dp_b: [112] f32
// depth out: f16 [pos][112] (z-contiguous for gridsample)
__global__ void __launch_bounds__(256) depth_proj_softmax_kernel(
    const _Float16* __restrict__ x, const _Float16* __restrict__ wdp,
    const float* __restrict__ dp_b, _Float16* __restrict__ depth) {
  const int wave = threadIdx.x >> 6, lane = threadIdx.x & 63;
  const int q = lane >> 4, l16 = lane & 15;
  const int pos0 = blockIdx.x * 64 + wave * 16;

  v4f acc[7];
#pragma unroll
  for (int nt = 0; nt < 7; ++nt) {
    float bv = dp_b[nt * 16 + l16];
    acc[nt] = {bv, bv, bv, bv};
  }
#pragma unroll
  for (int c0 = 0; c0 < 128; c0 += 32) {
    v8h a = *(const v8h*)(x + (size_t)(pos0 + l16) * 128 + c0 + q * 8);
#pragma unroll
    for (int nt = 0; nt < 7; ++nt) {
      v8h b = *(const v8h*)(wdp + (size_t)(nt * 16 + l16) * 128 + c0 + q * 8);
      acc[nt] = __builtin_amdgcn_mfma_f32_16x16x32_f16(a, b, acc[nt], 0, 0, 0);
    }
  }
  float m[4];
#pragma unroll
  for (int r = 0; r < 4; ++r) {
    m[r] = acc[0][r];
#pragma unroll
    for (int nt = 1; nt < 7; ++nt) m[r] = fmaxf(m[r], acc[nt][r]);
  }
#pragma unroll
  for (int off = 1; off < 16; off <<= 1)
#pragma unroll
    for (int r = 0; r < 4; ++r) m[r] = fmaxf(m[r], __shfl_xor(m[r], off));
  float s[4] = {0.f, 0.f, 0.f, 0.f};
#pragma unroll
  for (int nt = 0; nt < 7; ++nt)
#pragma unroll
    for (int r = 0; r < 4; ++r) {
      float e = expf(acc[nt][r] - m[r]);
      acc[nt][r] = e;
      s[r] += e;
    }
#pragma unroll
  for (int off = 1; off < 16; off <<= 1)
#pragma unroll
    for (int r = 0; r < 4; ++r) s[r] += __shfl_xor(s[r], off);
#pragma unroll
  for (int r = 0; r < 4; ++r) {
    const float inv = 1.f / s[r];
    const size_t p = pos0 + q * 4 + r;
#pragma unroll
    for (int nt = 0; nt < 7; ++nt)
      depth[p * 112 + nt * 16 + l16] = (_Float16)(acc[nt][r] * inv);
  }
}

// ---------------------------------------------------------------- trilinear grid sample (C=1)
__global__ void __launch_bounds__(256) gridsample_kernel(
    const float* __restrict__ grids, const _Float16* __restrict__ depth,
    float* __restrict__ out) {
  const int i = blockIdx.x * 256 + threadIdx.x;
  const int n = i >> 18;
  const float gx = grids[(size_t)i * 3];
  const float gy = grids[(size_t)i * 3 + 1];
  const float gz = grids[(size_t)i * 3 + 2];
  const float ix = (gx + 1.f) * 100.f - 0.5f;
  const float iy = (gy + 1.f) * 28.f - 0.5f;
  const float iz = (gz + 1.f) * 56.f - 0.5f;
  const float xf = floorf(ix), yf = floorf(iy), zf = floorf(iz);
  const int x0 = (int)xf, y0 = (int)yf, z0 = (int)zf;
  const float fx = ix - xf, fy = iy - yf, fz = iz - zf;
  const bool zv0 = (unsigned)z0 < 112u;
  const bool zv1 = (unsigned)(z0 + 1) < 112u;
  const float wz0 = 1.f - fz, wz1 = fz;
  float acc = 0.f;
#pragma unroll
  for (int dy = 0; dy < 2; ++dy) {
    const int yi = y0 + dy;
    const float wy = dy ? fy : 1.f - fy;
#pragma unroll
    for (int dx = 0; dx < 2; ++dx) {
      const int xi = x0 + dx;
      const float wx = dx ? fx : 1.f - fx;
      if ((unsigned)xi < 200u && (unsigned)yi < 56u) {
        const _Float16* bp = depth + ((size_t)n * 11200 + yi * 200 + xi) * 112;
        float v0 = zv0 ? (float)bp[z0] : 0.f;
        float v1 = zv1 ? (float)bp[z0 + 1] : 0.f;
        acc += (wx * wy) * (wz0 * v0 + wz1 * v1);
      }
    }
  }
  out[i] = acc;
}

// ---------------------------------------------------------------- launch
extern "C" void kernel_launch(void* const* d_in, const int* in_sizes, int n_in,
                              void* d_out, int out_size, void* d_ws, size_t ws_size,
                              hipStream_t stream) {
  (void)in_sizes; (void)n_in; (void)out_size; (void)ws_size;
  const float* img = (const float*)d_in[0];
  const float* sps = (const float*)d_in[1];
  const float* grids = (const float*)d_in[2];
  const float* rc_w = (const float*)d_in[3];
  const float* rc_b = (const float*)d_in[4];
  const float* rc_s = (const float*)d_in[5];
  const float* rc_t = (const float*)d_in[6];
  const float* fc1_w = (const float*)d_in[7];
  const float* fc1_b = (const float*)d_in[8];
  const float* fc2_w = (const float*)d_in[9];
  const float* fc2_b = (const float*)d_in[10];
  const float* se_rw = (const float*)d_in[11];
  const float* se_rb = (const float*)d_in[12];
  const float* se_ew = (const float*)d_in[13];
  const float* se_eb = (const float*)d_in[14];
  const float* bb_w1 = (const float*)d_in[15];
  const float* bb_s1 = (const float*)d_in[16];
  const float* bb_t1 = (const float*)d_in[17];
  const float* bb_w2 = (const float*)d_in[18];
  const float* bb_s2 = (const float*)d_in[19];
  const float* bb_t2 = (const float*)d_in[20];
  const float* dp_w = (const float*)d_in[21];
  const float* dp_b = (const float*)d_in[22];
  float* outp = (float*)d_out;

  char* ws = (char*)d_ws;
  _Float16* act16 = (_Float16*)(ws + 0);
  _Float16* depth16 = (_Float16*)(ws + 0);  // reuses act16 slot (act16 dead post rc-conv)
  _Float16* xa = (_Float16*)(ws + 23068672);
  _Float16* xb = (_Float16*)(ws + 23068672 + 11534336);
  _Float16* yb = (_Float16*)(ws + 23068672 + 2 * 11534336);
  _Float16* wrc = (_Float16*)(ws + 57671680);           // 589,824 B
  _Float16* wdp = (_Float16*)(ws + 57671680 + 589824);  // 28,672 B
  _Float16* wbb = (_Float16*)(ws + 58327040);           // 1,769,472 B
  float* sig = (float*)(ws + 58327040 + 1769472);       // 2,048 B

  prep_kernel<<<dim3(1032), 256, 0, stream>>>(
      rc_w, bb_w1, bb_w2, dp_w, img, sps, fc1_w, fc1_b, fc2_w, fc2_b, se_rw, se_rb,
      se_ew, se_eb, wrc, wbb, wdp, act16, sig);

  dim3 cgrid(7, 7, 8);  // 8h x 32w x 64cout, z = n*2 + cg, 392 blocks x 8 waves
  conv3x3_kernel<256, 0><<<cgrid, 512, 0, stream>>>(act16, wrc, nullptr, rc_b, rc_s,
                                                    rc_t, sig, xa);
  _Float16* xcur = xa;
  _Float16* xnxt = xb;
  for (int i = 0; i < 3; ++i) {
    conv3x3_kernel<128, 1><<<cgrid, 512, 0, stream>>>(
        xcur, wbb + (size_t)(2 * i) * 147456, nullptr, nullptr, bb_s1 + i * 128,
        bb_t1 + i * 128, nullptr, yb);
    conv3x3_kernel<128, 2><<<cgrid, 512, 0, stream>>>(
        yb, wbb + (size_t)(2 * i + 1) * 147456, xcur, nullptr, bb_s2 + i * 128,
        bb_t2 + i * 128, nullptr, xnxt);
    _Float16* t = xcur;
    xcur = xnxt;
    xnxt = t;
  }

  depth_proj_softmax_kernel<<<dim3(700), 256, 0, stream>>>(xcur, wdp, dp_b, depth16);
  gridsample_kernel<<<dim3(4096), 256, 0, stream>>>(grids, depth16, outp);
}